// Round 3
// baseline (2326.879 us; speedup 1.0000x reference)
//
#include <hip/hip_runtime.h>
#include <math.h>

// Problem constants
#define Qn 2048
#define Nn 64
#define Sn 128
#define An 4
#define En 128
#define TASKW 576  // N + 4*S
#define NEGV -1000000000.0f

// ---------------------------------------------------------------------------
// Packed fp32 math (v_pk_fma_f32: 2 x f32 per lane per issue).
// ---------------------------------------------------------------------------
typedef float v2f __attribute__((ext_vector_type(2)));
typedef float v4f __attribute__((ext_vector_type(4)));

__device__ __forceinline__ v2f mkv2(float a, float b) {
  v2f r; r.x = a; r.y = b; return r;
}
__device__ __forceinline__ v2f lo2(v4f v) { v2f r; r.x = v.x; r.y = v.y; return r; }
__device__ __forceinline__ v2f hi2(v4f v) { v2f r; r.x = v.z; r.y = v.w; return r; }
__device__ __forceinline__ void pkfma(v2f& d, v2f a, v2f b) {
  asm("v_pk_fma_f32 %0, %1, %2, %0" : "+v"(d) : "v"(a), "v"(b));
}
// d += broadcast(a.lo) * b   (op_sel routes src0.lo to both result halves)
__device__ __forceinline__ void pkfma_bl(v2f& d, v2f a, v2f b) {
  asm("v_pk_fma_f32 %0, %1, %2, %0 op_sel:[0,0,0] op_sel_hi:[0,1,1]"
      : "+v"(d) : "v"(a), "v"(b));
}
// d += broadcast(a.hi) * b
__device__ __forceinline__ void pkfma_bh(v2f& d, v2f a, v2f b) {
  asm("v_pk_fma_f32 %0, %1, %2, %0 op_sel:[1,0,0] op_sel_hi:[1,1,1]"
      : "+v"(d) : "v"(a), "v"(b));
}

// ---------------------------------------------------------------------------
// Threefry-2x32 (20 rounds), matches JAX's threefry2x32_p exactly.
// ---------------------------------------------------------------------------
__device__ __forceinline__ void threefry2x32(unsigned k0, unsigned k1,
                                             unsigned x0, unsigned x1,
                                             unsigned& o0, unsigned& o1) {
  unsigned ks2 = k0 ^ k1 ^ 0x1BD11BDAu;
  x0 += k0; x1 += k1;
#define TFR(r) { x0 += x1; x1 = (x1 << (r)) | (x1 >> (32 - (r))); x1 ^= x0; }
  TFR(13) TFR(15) TFR(26) TFR(6)
  x0 += k1;  x1 += ks2 + 1u;
  TFR(17) TFR(29) TFR(16) TFR(24)
  x0 += ks2; x1 += k0 + 2u;
  TFR(13) TFR(15) TFR(26) TFR(6)
  x0 += k0;  x1 += k1 + 3u;
  TFR(17) TFR(29) TFR(16) TFR(24)
  x0 += k1;  x1 += ks2 + 4u;
  TFR(13) TFR(15) TFR(26) TFR(6)
  x0 += ks2; x1 += k0 + 5u;
#undef TFR
  o0 = x0; o1 = x1;
}

__device__ __forceinline__ float silu_f(float x) {
  return x / (1.0f + expf(-x));
}
__device__ __forceinline__ float fexp(float x) {
  return __builtin_amdgcn_exp2f(x * 1.44269504088896f);
}
__device__ __forceinline__ float fsilu(float x) {
  const float e = __builtin_amdgcn_exp2f(x * -1.44269504088896f);
  return x * __builtin_amdgcn_rcpf(1.0f + e);
}
__device__ __forceinline__ float flog(float x) {
  return __builtin_amdgcn_logf(x) * 0.69314718055995f;
}

// ---------------------------------------------------------------------------
// Setup: Mt4 = lane-interleaved M (M = w_node2 @ w_ser2^T), dvec, PRNG keys.
// Mt4 layout: element (j,h) stored at Mt4[((j>>2)*128 + h)*4 + (j&3)] so a
// wave of 128 threads (h = tid) reading j-block j4 issues coalesced b128.
// ---------------------------------------------------------------------------
__global__ void setup_kernel(const float* __restrict__ w_node2,
                             const float* __restrict__ b_node2,
                             const float* __restrict__ w_ser2,
                             const float* __restrict__ b_ser2,
                             float* __restrict__ Mt4, float* __restrict__ dvec,
                             unsigned* __restrict__ keys) {
  const int b = blockIdx.x, t = threadIdx.x;
  if (b < 128) {
    float acc = 0.0f;
    for (int e = 0; e < 128; ++e)
      acc = fmaf(w_node2[b * 128 + e], w_ser2[t * 128 + e], acc);
    Mt4[(((b >> 2) * 128) + t) * 4 + (b & 3)] = acc;
  } else if (b == 128) {
    float acc = 0.0f;
    for (int e = 0; e < 128; ++e)
      acc = fmaf(b_node2[e], w_ser2[t * 128 + e], acc);
    dvec[t] = acc;
  } else {
    if (t < 64) {
      unsigned o0, o1;
      threefry2x32(0u, 1u, 0u, (unsigned)t, o0, o1);
      keys[2 * t + 0] = o0;
      keys[2 * t + 1] = o1;
    }
  }
}

// ---------------------------------------------------------------------------
// K1: node_emb = silu(concat(tasks[:,:, :64], cons) @ w1 + b1) @ w2 + b2
// ---------------------------------------------------------------------------
__global__ __launch_bounds__(256, 2)
void init_mlp_kernel(const float* __restrict__ tasks,
                     const float* __restrict__ cons,
                     const float* __restrict__ w1, const float* __restrict__ b1,
                     const float* __restrict__ w2, const float* __restrict__ b2,
                     float* __restrict__ node_emb) {
  const int q = blockIdx.x, tid = threadIdx.x;
  const int lane = tid & 127, half = tid >> 7;
  __shared__ __align__(16) float xr[2][68];
  __shared__ __align__(16) float sgb[2][128];
  v2f w1p[34], w2p[64];
#pragma unroll
  for (int i = 0; i < 34; ++i)
    w1p[i] = mkv2(w1[(2 * i) * 128 + lane], w1[(2 * i + 1) * 128 + lane]);
#pragma unroll
  for (int j = 0; j < 64; ++j)
    w2p[j] = mkv2(w2[(2 * j) * 128 + lane], w2[(2 * j + 1) * 128 + lane]);
  const float bb1 = b1[lane], bb2 = b2[lane];
  for (int r = 0; r < 64; r += 2) {
    if (tid < 136) {
      const int rr = tid / 68, j = tid - rr * 68;
      xr[rr][j] = (j < 64) ? tasks[(q * 64 + r + rr) * TASKW + j]
                           : cons[q * 4 + (j - 64)];
    }
    __syncthreads();
    v2f gp = mkv2(0.0f, 0.0f);
    const v4f* xr4 = (const v4f*)&xr[half][0];
#pragma unroll
    for (int i = 0; i < 17; ++i) {
      const v4f x = xr4[i];
      pkfma(gp, lo2(x), w1p[2 * i]);
      pkfma(gp, hi2(x), w1p[2 * i + 1]);
    }
    const float g = gp.x + gp.y + bb1;
    sgb[half][lane] = silu_f(g);
    __syncthreads();
    v2f op = mkv2(0.0f, 0.0f);
    const v4f* sgb4 = (const v4f*)&sgb[half][0];
#pragma unroll
    for (int j = 0; j < 32; ++j) {
      const v4f s = sgb4[j];
      pkfma(op, lo2(s), w2p[2 * j]);
      pkfma(op, hi2(s), w2p[2 * j + 1]);
    }
    node_emb[(q * 64 + r + half) * 128 + lane] = op.x + op.y + bb2;
    __syncthreads();
  }
}

// ---------------------------------------------------------------------------
// K2: fused MHA (QKV + scores + softmax + AV), b128 LDS reads throughout.
// ---------------------------------------------------------------------------
__global__ __launch_bounds__(256, 2)
void mha_kernel(const float* __restrict__ node_emb,
                const float* __restrict__ wq, const float* __restrict__ bq,
                const float* __restrict__ wk, const float* __restrict__ bk,
                const float* __restrict__ wv, const float* __restrict__ bv,
                float* __restrict__ y_out) {
  const int q = blockIdx.x, tid = threadIdx.x;
  __shared__ __align__(16) float xs[64][132];
  __shared__ __align__(16) float qh[64][20];
  __shared__ __align__(16) float kh[64][20];
  __shared__ __align__(16) float vt[16][68];
  __shared__ __align__(16) float pool[3 * 16 * 132];  // wht[3][16][132] U at[64][68]
  float (*wht)[16][132] = (float (*)[16][132])pool;
  float (*at)[68] = (float (*)[68])pool;

  for (int idx = tid; idx < 64 * 32; idx += 256) {
    const int n = idx >> 5, e4 = idx & 31;
    *(v4f*)&xs[n][4 * e4] =
        *(const v4f*)&node_emb[(q * 64 + n) * 128 + 4 * e4];
  }
  __syncthreads();

  const int d16 = tid >> 4;  // 0..15
  const int ng = tid & 15;   // 0..15

  for (int hd = 0; hd < 8; ++hd) {
    for (int idx = tid; idx < 3 * 128 * 16; idx += 256) {
      const int m = idx >> 11, k = (idx >> 4) & 127, d = idx & 15;
      const float* W = (m == 0) ? wq : (m == 1) ? wk : wv;
      wht[m][d][k] = W[k * 128 + hd * 16 + d];
    }
    __syncthreads();

    {
      const float bqv = bq[hd * 16 + d16];
      const float bkv = bk[hd * 16 + d16];
      const float bvv = bv[hd * 16 + d16];
      const v4f* wq4 = (const v4f*)&wht[0][d16][0];
      const v4f* wk4 = (const v4f*)&wht[1][d16][0];
      const v4f* wv4 = (const v4f*)&wht[2][d16][0];
      const v4f* xr0 = (const v4f*)&xs[ng][0];
      const v4f* xr1 = (const v4f*)&xs[ng + 16][0];
      const v4f* xr2 = (const v4f*)&xs[ng + 32][0];
      const v4f* xr3 = (const v4f*)&xs[ng + 48][0];
      v2f aq0 = mkv2(0, 0), aq1 = mkv2(0, 0), aq2 = mkv2(0, 0), aq3 = mkv2(0, 0);
      v2f ak0 = mkv2(0, 0), ak1 = mkv2(0, 0), ak2 = mkv2(0, 0), ak3 = mkv2(0, 0);
      v2f av0 = mkv2(0, 0), av1 = mkv2(0, 0), av2 = mkv2(0, 0), av3 = mkv2(0, 0);
#pragma unroll 4
      for (int kk = 0; kk < 32; ++kk) {
        const v4f wqv = wq4[kk], wkv = wk4[kk], wvv = wv4[kk];
        const v4f x0 = xr0[kk], x1 = xr1[kk], x2 = xr2[kk], x3 = xr3[kk];
        const v2f wqa = lo2(wqv), wqb = hi2(wqv);
        const v2f wka = lo2(wkv), wkb = hi2(wkv);
        const v2f wva = lo2(wvv), wvb = hi2(wvv);
        const v2f x0a = lo2(x0), x0b = hi2(x0);
        const v2f x1a = lo2(x1), x1b = hi2(x1);
        const v2f x2a = lo2(x2), x2b = hi2(x2);
        const v2f x3a = lo2(x3), x3b = hi2(x3);
        pkfma(aq0, x0a, wqa); pkfma(aq0, x0b, wqb);
        pkfma(aq1, x1a, wqa); pkfma(aq1, x1b, wqb);
        pkfma(aq2, x2a, wqa); pkfma(aq2, x2b, wqb);
        pkfma(aq3, x3a, wqa); pkfma(aq3, x3b, wqb);
        pkfma(ak0, x0a, wka); pkfma(ak0, x0b, wkb);
        pkfma(ak1, x1a, wka); pkfma(ak1, x1b, wkb);
        pkfma(ak2, x2a, wka); pkfma(ak2, x2b, wkb);
        pkfma(ak3, x3a, wka); pkfma(ak3, x3b, wkb);
        pkfma(av0, x0a, wva); pkfma(av0, x0b, wvb);
        pkfma(av1, x1a, wva); pkfma(av1, x1b, wvb);
        pkfma(av2, x2a, wva); pkfma(av2, x2b, wvb);
        pkfma(av3, x3a, wva); pkfma(av3, x3b, wvb);
      }
      qh[ng][d16] = fmaxf(aq0.x + aq0.y + bqv, 0.0f);
      qh[ng + 16][d16] = fmaxf(aq1.x + aq1.y + bqv, 0.0f);
      qh[ng + 32][d16] = fmaxf(aq2.x + aq2.y + bqv, 0.0f);
      qh[ng + 48][d16] = fmaxf(aq3.x + aq3.y + bqv, 0.0f);
      kh[ng][d16] = fmaxf(ak0.x + ak0.y + bkv, 0.0f);
      kh[ng + 16][d16] = fmaxf(ak1.x + ak1.y + bkv, 0.0f);
      kh[ng + 32][d16] = fmaxf(ak2.x + ak2.y + bkv, 0.0f);
      kh[ng + 48][d16] = fmaxf(ak3.x + ak3.y + bkv, 0.0f);
      vt[d16][ng] = fmaxf(av0.x + av0.y + bvv, 0.0f);
      vt[d16][ng + 16] = fmaxf(av1.x + av1.y + bvv, 0.0f);
      vt[d16][ng + 32] = fmaxf(av2.x + av2.y + bvv, 0.0f);
      vt[d16][ng + 48] = fmaxf(av3.x + av3.y + bvv, 0.0f);
    }
    __syncthreads();

    {
      const int n = tid >> 2, mg = tid & 3;
      v4f qv[4];
      const v4f* qrow = (const v4f*)&qh[n][0];
#pragma unroll
      for (int kk = 0; kk < 4; ++kk) qv[kk] = qrow[kk];
#pragma unroll 4
      for (int jj = 0; jj < 16; ++jj) {
        const int m = mg + 4 * jj;
        const v4f* krow = (const v4f*)&kh[m][0];
        v2f accp = mkv2(0.0f, 0.0f);
#pragma unroll
        for (int kk = 0; kk < 4; ++kk) {
          const v4f kv = krow[kk];
          pkfma(accp, lo2(qv[kk]), lo2(kv));
          pkfma(accp, hi2(qv[kk]), hi2(kv));
        }
        at[n][m] = (accp.x + accp.y) * 0.25f;
      }
    }
    __syncthreads();

    {
      const int r = tid >> 2, p = tid & 3;
      const v4f* arow = (const v4f*)&at[r][p * 16];
      v4f av[4];
#pragma unroll
      for (int u = 0; u < 4; ++u) av[u] = arow[u];
      float mx = -1e30f;
#pragma unroll
      for (int u = 0; u < 4; ++u) {
        mx = fmaxf(mx, fmaxf(fmaxf(av[u].x, av[u].y), fmaxf(av[u].z, av[u].w)));
      }
      mx = fmaxf(mx, __shfl_xor(mx, 1, 64));
      mx = fmaxf(mx, __shfl_xor(mx, 2, 64));
      float s = 0.0f;
#pragma unroll
      for (int u = 0; u < 4; ++u) {
        av[u].x = fexp(av[u].x - mx); av[u].y = fexp(av[u].y - mx);
        av[u].z = fexp(av[u].z - mx); av[u].w = fexp(av[u].w - mx);
        s += av[u].x + av[u].y + av[u].z + av[u].w;
      }
      s += __shfl_xor(s, 1, 64);
      s += __shfl_xor(s, 2, 64);
      const float rs = __builtin_amdgcn_rcpf(s);
      v4f* wrow = (v4f*)&at[r][p * 16];
#pragma unroll
      for (int u = 0; u < 4; ++u) {
        av[u].x *= rs; av[u].y *= rs; av[u].z *= rs; av[u].w *= rs;
        wrow[u] = av[u];
      }
    }
    __syncthreads();

    {
      const int dd = tid & 15, ngr = tid >> 4;
      const v4f* vrow = (const v4f*)&vt[dd][0];
      const v4f* ar0 = (const v4f*)&at[ngr][0];
      const v4f* ar1 = (const v4f*)&at[ngr + 16][0];
      const v4f* ar2 = (const v4f*)&at[ngr + 32][0];
      const v4f* ar3 = (const v4f*)&at[ngr + 48][0];
      v2f ac0 = mkv2(0, 0), ac1 = mkv2(0, 0), ac2 = mkv2(0, 0), ac3 = mkv2(0, 0);
#pragma unroll 4
      for (int kk = 0; kk < 16; ++kk) {
        const v4f vv = vrow[kk];
        const v2f va = lo2(vv), vb = hi2(vv);
        const v4f a0 = ar0[kk], a1 = ar1[kk], a2 = ar2[kk], a3 = ar3[kk];
        pkfma(ac0, lo2(a0), va); pkfma(ac0, hi2(a0), vb);
        pkfma(ac1, lo2(a1), va); pkfma(ac1, hi2(a1), vb);
        pkfma(ac2, lo2(a2), va); pkfma(ac2, hi2(a2), vb);
        pkfma(ac3, lo2(a3), va); pkfma(ac3, hi2(a3), vb);
      }
      y_out[(q * 64 + ngr) * 128 + hd * 16 + dd] = ac0.x + ac0.y;
      y_out[(q * 64 + ngr + 16) * 128 + hd * 16 + dd] = ac1.x + ac1.y;
      y_out[(q * 64 + ngr + 32) * 128 + hd * 16 + dd] = ac2.x + ac2.y;
      y_out[(q * 64 + ngr + 48) * 128 + hd * 16 + dd] = ac3.x + ac3.y;
    }
    __syncthreads();
  }
}

// ---------------------------------------------------------------------------
// K3 (fused): nodes = relu(y @ wo + bo) + resid; gbase = nodes @ w_node1 + b
// ---------------------------------------------------------------------------
__global__ __launch_bounds__(256, 2)
void outgb_kernel(const float* __restrict__ resid, const float* __restrict__ y,
                  const float* __restrict__ wo, const float* __restrict__ bo,
                  const float* __restrict__ w_node1,
                  const float* __restrict__ b_node1,
                  float* __restrict__ gbase) {
  const int q = blockIdx.x, tid = threadIdx.x;
  __shared__ __align__(16) float ys[64][132];
  __shared__ __align__(16) float wot[32][132];
  for (int idx = tid; idx < 64 * 32; idx += 256) {
    const int n = idx >> 5, e4 = idx & 31;
    *(v4f*)&ys[n][4 * e4] = *(const v4f*)&y[(q * 64 + n) * 128 + 4 * e4];
  }
  const int cg = tid & 15, ngr = tid >> 4;
  float nodes[4][8];  // [n-group][tile*2 + {0,1}]

#pragma unroll
  for (int tile = 0; tile < 4; ++tile) {
    const int c0 = 32 * tile;
    __syncthreads();
    for (int idx = tid; idx < 32 * 128; idx += 256) {
      const int k = idx >> 5, c = idx & 31;
      wot[c][k] = wo[k * 128 + c0 + c];
    }
    __syncthreads();
    const int c = c0 + 2 * cg;
    const v4f* w0 = (const v4f*)&wot[2 * cg][0];
    const v4f* w1 = (const v4f*)&wot[2 * cg + 1][0];
    const v4f* yr0 = (const v4f*)&ys[ngr][0];
    const v4f* yr1 = (const v4f*)&ys[ngr + 16][0];
    const v4f* yr2 = (const v4f*)&ys[ngr + 32][0];
    const v4f* yr3 = (const v4f*)&ys[ngr + 48][0];
    v2f a00 = mkv2(0, 0), a01 = mkv2(0, 0), a10 = mkv2(0, 0), a11 = mkv2(0, 0);
    v2f a20 = mkv2(0, 0), a21 = mkv2(0, 0), a30 = mkv2(0, 0), a31 = mkv2(0, 0);
#pragma unroll 4
    for (int kk = 0; kk < 32; ++kk) {
      const v4f wv0 = w0[kk], wv1 = w1[kk];
      const v2f w0a = lo2(wv0), w0b = hi2(wv0);
      const v2f w1a = lo2(wv1), w1b = hi2(wv1);
      const v4f x0 = yr0[kk], x1 = yr1[kk], x2 = yr2[kk], x3 = yr3[kk];
      pkfma(a00, lo2(x0), w0a); pkfma(a00, hi2(x0), w0b);
      pkfma(a01, lo2(x0), w1a); pkfma(a01, hi2(x0), w1b);
      pkfma(a10, lo2(x1), w0a); pkfma(a10, hi2(x1), w0b);
      pkfma(a11, lo2(x1), w1a); pkfma(a11, hi2(x1), w1b);
      pkfma(a20, lo2(x2), w0a); pkfma(a20, hi2(x2), w0b);
      pkfma(a21, lo2(x2), w1a); pkfma(a21, hi2(x2), w1b);
      pkfma(a30, lo2(x3), w0a); pkfma(a30, hi2(x3), w0b);
      pkfma(a31, lo2(x3), w1a); pkfma(a31, hi2(x3), w1b);
    }
    const float b0v = bo[c], b1v = bo[c + 1];
#define PROJ_EMIT(J, A0, A1)                                                  \
    {                                                                         \
      const int n = ngr + 16 * J;                                             \
      const float2 res = *(const float2*)&resid[(q * 64 + n) * 128 + c];      \
      nodes[J][2 * tile] = fmaxf(A0.x + A0.y + b0v, 0.0f) + res.x;            \
      nodes[J][2 * tile + 1] = fmaxf(A1.x + A1.y + b1v, 0.0f) + res.y;        \
    }
    PROJ_EMIT(0, a00, a01)
    PROJ_EMIT(1, a10, a11)
    PROJ_EMIT(2, a20, a21)
    PROJ_EMIT(3, a30, a31)
#undef PROJ_EMIT
  }
  __syncthreads();
#pragma unroll
  for (int j = 0; j < 4; ++j) {
    const int n = ngr + 16 * j;
#pragma unroll
    for (int tile = 0; tile < 4; ++tile) {
      *(float2*)&ys[n][32 * tile + 2 * cg] =
          make_float2(nodes[j][2 * tile], nodes[j][2 * tile + 1]);
    }
  }

#pragma unroll
  for (int tile = 0; tile < 4; ++tile) {
    const int c0 = 32 * tile;
    __syncthreads();
    for (int idx = tid; idx < 32 * 128; idx += 256) {
      const int k = idx >> 5, c = idx & 31;
      wot[c][k] = w_node1[k * 128 + c0 + c];
    }
    __syncthreads();
    const int c = c0 + 2 * cg;
    const v4f* w0 = (const v4f*)&wot[2 * cg][0];
    const v4f* w1 = (const v4f*)&wot[2 * cg + 1][0];
    const v4f* yr0 = (const v4f*)&ys[ngr][0];
    const v4f* yr1 = (const v4f*)&ys[ngr + 16][0];
    const v4f* yr2 = (const v4f*)&ys[ngr + 32][0];
    const v4f* yr3 = (const v4f*)&ys[ngr + 48][0];
    v2f a00 = mkv2(0, 0), a01 = mkv2(0, 0), a10 = mkv2(0, 0), a11 = mkv2(0, 0);
    v2f a20 = mkv2(0, 0), a21 = mkv2(0, 0), a30 = mkv2(0, 0), a31 = mkv2(0, 0);
#pragma unroll 4
    for (int kk = 0; kk < 32; ++kk) {
      const v4f wv0 = w0[kk], wv1 = w1[kk];
      const v2f w0a = lo2(wv0), w0b = hi2(wv0);
      const v2f w1a = lo2(wv1), w1b = hi2(wv1);
      const v4f x0 = yr0[kk], x1 = yr1[kk], x2 = yr2[kk], x3 = yr3[kk];
      pkfma(a00, lo2(x0), w0a); pkfma(a00, hi2(x0), w0b);
      pkfma(a01, lo2(x0), w1a); pkfma(a01, hi2(x0), w1b);
      pkfma(a10, lo2(x1), w0a); pkfma(a10, hi2(x1), w0b);
      pkfma(a11, lo2(x1), w1a); pkfma(a11, hi2(x1), w1b);
      pkfma(a20, lo2(x2), w0a); pkfma(a20, hi2(x2), w0b);
      pkfma(a21, lo2(x2), w1a); pkfma(a21, hi2(x2), w1b);
      pkfma(a30, lo2(x3), w0a); pkfma(a30, hi2(x3), w0b);
      pkfma(a31, lo2(x3), w1a); pkfma(a31, hi2(x3), w1b);
    }
    const float b0v = b_node1[c], b1v = b_node1[c + 1];
#define GB_EMIT(J, A0, A1)                                                    \
    {                                                                         \
      const int n = ngr + 16 * J;                                             \
      float2 o;                                                               \
      o.x = A0.x + A0.y + b0v;                                                \
      o.y = A1.x + A1.y + b1v;                                                \
      *(float2*)&gbase[(q * 64 + n) * 128 + c] = o;                           \
    }
    GB_EMIT(0, a00, a01)
    GB_EMIT(1, a10, a11)
    GB_EMIT(2, a20, a21)
    GB_EMIT(3, a30, a31)
#undef GB_EMIT
  }
}

// ---------------------------------------------------------------------------
// K4: 64-step scan, one workgroup per q. v3: no register-resident M (reads
// lane-interleaved Mt4 from L2 each step) -> no spill at high occupancy;
// 4 barriers/step; all 4 waves busy every phase; logits spread over all 256
// threads (16 threads / 4 services, op_sel-broadcast pk_fma).
// ---------------------------------------------------------------------------
__global__ __launch_bounds__(256, 6)
void scan_kernel(const float* __restrict__ tasks, const int* __restrict__ masks,
                 const int* __restrict__ topologicals,
                 const float* __restrict__ w_node1,
                 const float* __restrict__ w_ser1,
                 const float* __restrict__ b_ser1,
                 const float* __restrict__ gbase,
                 const float* __restrict__ Mt4, const float* __restrict__ dvec,
                 const unsigned* __restrict__ keys, float* __restrict__ out) {
  const int q = blockIdx.x, tid = threadIdx.x;
  const int wl = tid & 63, wave = tid >> 6;
  const int g16 = tid >> 4, oo = tid & 15;

  __shared__ __align__(16) float task_s[2][TASKW];
  __shared__ __align__(16) float gb_s[2][128];
  __shared__ int mask_s[2][128];
  __shared__ int topo_s[64];
  __shared__ __align__(16) float sg[128];
  __shared__ __align__(16) v4f wa_s[64];   // w_ser1 pairs, cols 0,1
  __shared__ __align__(16) v4f wb_s[64];   // w_ser1 pairs, cols 2,3
  __shared__ __align__(16) v2f bp_s[64];   // b_ser1 pairs
  __shared__ __align__(16) v2f up_s[64];   // uu pairs (per step)
  __shared__ float gn_s[128];              // gumbel noise, compact order
  __shared__ float lcomp_s[128];           // logits, compact order
  __shared__ int act_s[128];               // active service indices
  __shared__ float qr_s[64];               // qos col 0 (only live column)
  __shared__ float ridx_s[64], rprob_s[64];
  __shared__ unsigned keys_s[128];
  __shared__ int na_s;

  if (tid < 64) {
    topo_s[tid] = topologicals[q * 64 + tid];
    const int j = tid;
    v4f wa, wb;
    wa.x = w_ser1[0 * 128 + 2 * j]; wa.y = w_ser1[0 * 128 + 2 * j + 1];
    wa.z = w_ser1[1 * 128 + 2 * j]; wa.w = w_ser1[1 * 128 + 2 * j + 1];
    wb.x = w_ser1[2 * 128 + 2 * j]; wb.y = w_ser1[2 * 128 + 2 * j + 1];
    wb.z = w_ser1[3 * 128 + 2 * j]; wb.w = w_ser1[3 * 128 + 2 * j + 1];
    wa_s[j] = wa;
    wb_s[j] = wb;
    bp_s[j] = mkv2(b_ser1[2 * j], b_ser1[2 * j + 1]);
    qr_s[tid] = 3.0f;
    ridx_s[tid] = 0.0f;
    rprob_s[tid] = 0.0f;
  }
  float dv_r = 0.0f;
  v4f qp_r; qp_r.x = 0; qp_r.y = 0; qp_r.z = 0; qp_r.w = 0;
  if (tid < 128) {
    keys_s[tid] = keys[tid];
    dv_r = dvec[tid];
    qp_r.x = w_node1[128 * 128 + tid];
    qp_r.y = w_node1[129 * 128 + tid];
    qp_r.z = w_node1[130 * 128 + tid];
    qp_r.w = w_node1[131 * 128 + tid];
  }
  float ava = 1.0f, tp = 3.0f, rel = 1.0f;  // per-thread redundant state
  __syncthreads();

  // Prologue: stage step 0 into buffer 0
  {
    const int topo0 = topo_s[63];
    if (tid < 144)
      ((float4*)task_s[0])[tid] =
          ((const float4*)(tasks + (size_t)(q * 64 + topo0) * TASKW))[tid];
    if (tid < 128) {
      gb_s[0][tid] = gbase[(q * 64 + topo0) * 128 + tid];
      mask_s[0][tid] = masks[(q * 64 + topo0) * 128 + tid];
    }
  }
  __syncthreads();

  for (int t = 0; t < 64; ++t) {
    const int cur = t & 1, nxt = cur ^ 1;
    const int topo = topo_s[63 - t];
    const int tn = (t < 63) ? t + 1 : 63;
    const int ntopo = topo_s[63 - tn];

    // --- Phase 1: waves 0/1 rt + sg; wave 2 prefetch gb/mask + compact;
    // wave 3 prefetch task rows.
    float rt = 0.0f;
    float4 pf_t[3];
    float pf_g0 = 0.0f, pf_g1 = 0.0f;
    int pf_m0 = 0, pf_m1 = 0;
    if (wave < 2) {
      float p = task_s[cur][wl] * qr_s[wl];
#pragma unroll
      for (int o = 32; o > 0; o >>= 1) p = fmaxf(p, __shfl_xor(p, o, 64));
      rt = p;
      float g = gb_s[cur][tid];
      g = fmaf(rt, qp_r.x, g);
      g = fmaf(ava, qp_r.y, g);
      g = fmaf(tp, qp_r.z, g);
      g = fmaf(rel, qp_r.w, g);
      sg[tid] = fsilu(g);
    } else if (wave == 2) {
      pf_g0 = gbase[(q * 64 + ntopo) * 128 + wl];
      pf_g1 = gbase[(q * 64 + ntopo) * 128 + wl + 64];
      pf_m0 = masks[(q * 64 + ntopo) * 128 + wl];
      pf_m1 = masks[(q * 64 + ntopo) * 128 + wl + 64];
      const int m0 = mask_s[cur][wl] != 0;
      const int m1 = mask_s[cur][wl + 64] != 0;
      const unsigned long long b0 = __ballot(m0);
      const unsigned long long b1 = __ballot(m1);
      const unsigned long long lt = (1ull << wl) - 1ull;
      const int c0 = __popcll(b0);
      if (m0) act_s[__popcll(b0 & lt)] = wl;
      if (m1) act_s[c0 + __popcll(b1 & lt)] = wl + 64;
      if (wl == 0) na_s = c0 + __popcll(b1);
    } else {
#pragma unroll
      for (int r = 0; r < 3; ++r) {
        const int idx = wl + 64 * r;
        if (idx < 144)
          pf_t[r] =
              ((const float4*)(tasks + (size_t)(q * 64 + ntopo) * TASKW))[idx];
      }
    }
    __syncthreads();  // B_a : sg, act, na visible
    const int na = na_s;

    // --- Phase 2: waves 0/1 matvec u = sg @ M + dvec from L2-resident Mt4;
    // waves 2/3 gumbel-noise precompute for active slots.
    if (tid < 128) {
      v2f a0 = mkv2(0.0f, 0.0f), a1 = mkv2(0.0f, 0.0f);
      const v4f* Mg = ((const v4f*)Mt4) + tid;
      const v4f* sg4 = (const v4f*)sg;
#pragma unroll 8
      for (int j4 = 0; j4 < 32; ++j4) {
        const v4f m = Mg[j4 * 128];
        const v4f s = sg4[j4];
        pkfma(a0, lo2(s), lo2(m));
        pkfma(a1, hi2(s), hi2(m));
      }
      const float u = a0.x + a0.y + a1.x + a1.y + dv_r;
      const float u2 = __shfl_xor(u, 1, 64);
      if ((tid & 1) == 0) up_s[tid >> 1] = mkv2(u, u2);
    } else {
      const int slot = tid - 128;
      if (slot < na) {
        const int s = act_s[slot];
        unsigned o0, o1;
        threefry2x32(keys_s[2 * t], keys_s[2 * t + 1], 0u,
                     (unsigned)(q * 128 + s), o0, o1);
        const unsigned bits = o0 ^ o1;
        const float f = __uint_as_float((bits >> 9) | 0x3f800000u) - 1.0f;
        const float uu = (f > 0.0f) ? f : 1.17549435e-38f;
        gn_s[slot] = -flog(-flog(uu));
      }
    }
    __syncthreads();  // B_b : up, gn visible

    // --- Phase 3: land prefetched rows (waves 2/3), logits on all threads.
    if (wave == 3) {
#pragma unroll
      for (int r = 0; r < 3; ++r) {
        const int idx = wl + 64 * r;
        if (idx < 144) ((float4*)task_s[nxt])[idx] = pf_t[r];
      }
    } else if (wave == 2) {
      gb_s[nxt][wl] = pf_g0;
      gb_s[nxt][wl + 64] = pf_g1;
      mask_s[nxt][wl] = pf_m0;
      mask_s[nxt][wl + 64] = pf_m1;
    }

    auto logits_block = [&](const int sl0) {
      const int s0 = (sl0 + 0 < na) ? act_s[sl0 + 0] : 0;
      const int s1 = (sl0 + 1 < na) ? act_s[sl0 + 1] : 0;
      const int s2 = (sl0 + 2 < na) ? act_s[sl0 + 2] : 0;
      const int s3 = (sl0 + 3 < na) ? act_s[sl0 + 3] : 0;
      const v4f svA = *(const v4f*)&task_s[cur][64 + 4 * s0];
      const v4f svB = *(const v4f*)&task_s[cur][64 + 4 * s1];
      const v4f svC = *(const v4f*)&task_s[cur][64 + 4 * s2];
      const v4f svD = *(const v4f*)&task_s[cur][64 + 4 * s3];
      v2f ac0 = mkv2(0.0f, 0.0f), ac1 = mkv2(0.0f, 0.0f);
      v2f ac2 = mkv2(0.0f, 0.0f), ac3 = mkv2(0.0f, 0.0f);
#pragma unroll
      for (int jj = 0; jj < 4; ++jj) {
        const int j = oo + 16 * jj;
        const v4f wA = wa_s[j];
        const v4f wB = wb_s[j];
        const v2f bp = bp_s[j];
        const v2f up = up_s[j];
#define SRV(AC, SV)                                                           \
        {                                                                     \
          v2f p = bp;                                                         \
          pkfma_bl(p, lo2(SV), lo2(wA));                                      \
          pkfma_bh(p, lo2(SV), hi2(wA));                                      \
          pkfma_bl(p, hi2(SV), lo2(wB));                                      \
          pkfma_bh(p, hi2(SV), hi2(wB));                                      \
          const float ex = __builtin_amdgcn_exp2f(p.x * -1.44269504088896f);  \
          const float ey = __builtin_amdgcn_exp2f(p.y * -1.44269504088896f);  \
          const float rx = __builtin_amdgcn_rcpf(1.0f + ex);                  \
          const float ry = __builtin_amdgcn_rcpf(1.0f + ey);                  \
          pkfma(AC, mkv2(p.x * rx, p.y * ry), up);                            \
        }
        SRV(ac0, svA)
        SRV(ac1, svB)
        SRV(ac2, svC)
        SRV(ac3, svD)
#undef SRV
      }
      float l0 = ac0.x + ac0.y, l1 = ac1.x + ac1.y;
      float l2 = ac2.x + ac2.y, l3 = ac3.x + ac3.y;
      l0 += __shfl_xor(l0, 1, 64); l0 += __shfl_xor(l0, 2, 64);
      l0 += __shfl_xor(l0, 4, 64); l0 += __shfl_xor(l0, 8, 64);
      l1 += __shfl_xor(l1, 1, 64); l1 += __shfl_xor(l1, 2, 64);
      l1 += __shfl_xor(l1, 4, 64); l1 += __shfl_xor(l1, 8, 64);
      l2 += __shfl_xor(l2, 1, 64); l2 += __shfl_xor(l2, 2, 64);
      l2 += __shfl_xor(l2, 4, 64); l2 += __shfl_xor(l2, 8, 64);
      l3 += __shfl_xor(l3, 1, 64); l3 += __shfl_xor(l3, 2, 64);
      l3 += __shfl_xor(l3, 4, 64); l3 += __shfl_xor(l3, 8, 64);
      if (oo == 0) {
        if (sl0 + 3 < na) {
          *(float4*)&lcomp_s[sl0] = make_float4(l0, l1, l2, l3);
        } else {
          if (sl0 + 0 < na) lcomp_s[sl0 + 0] = l0;
          if (sl0 + 1 < na) lcomp_s[sl0 + 1] = l1;
          if (sl0 + 2 < na) lcomp_s[sl0 + 2] = l2;
        }
      }
    };
    if (16 * wave < na) logits_block(4 * g16);
    if (64 + 16 * wave < na) logits_block(64 + 4 * g16);
    __syncthreads();  // B_c : lcomp visible

    // --- Phase 4: per-wave redundant argmax; wave 3 softmax normalizer;
    // state update on all threads.
    float la = -3.0e38f, lb = -3.0e38f;
    if (wl < na) la = lcomp_s[wl] + gn_s[wl];
    if (wl + 64 < na) lb = lcomp_s[wl + 64] + gn_s[wl + 64];
    float z = la;
    int zi = wl;
    if (lb > z) { z = lb; zi = wl + 64; }
#pragma unroll
    for (int o = 32; o > 0; o >>= 1) {
      const float zo = __shfl_xor(z, o, 64);
      const int io = __shfl_xor(zi, o, 64);
      if (zo > z || (zo == z && io < zi)) { z = zo; zi = io; }
    }
    const int si = act_s[zi];
    if (wave == 3) {
      const float ma = (wl < na) ? lcomp_s[wl] : -3.0e38f;
      const float mb = (wl + 64 < na) ? lcomp_s[wl + 64] : -3.0e38f;
      float mx = fmaxf(ma, mb);
#pragma unroll
      for (int o = 32; o > 0; o >>= 1) mx = fmaxf(mx, __shfl_xor(mx, o, 64));
      float e = fexp(ma - mx) + fexp(mb - mx);
#pragma unroll
      for (int o = 32; o > 0; o >>= 1) e += __shfl_xor(e, o, 64);
      if (wl == 0)
        rprob_s[topo] += fexp(lcomp_s[zi] - mx) * __builtin_amdgcn_rcpf(e);
    }
    {
      const float s1v = task_s[cur][64 + 4 * si + 1];
      const float s2v = task_s[cur][64 + 4 * si + 2];
      const float s3v = task_s[cur][64 + 4 * si + 3];
      if (tid == 0) {
        const float s0v = task_s[cur][64 + 4 * si];
        qr_s[topo] = s0v + rt;
        ridx_s[topo] += (float)si;
      }
      ava = s1v * ava;
      tp = fminf(s2v, tp);
      rel = s3v * rel;
    }
    __syncthreads();  // B_final
  }
  if (tid < 64) {
    out[q * 64 + tid] = ridx_s[tid];
    out[Qn * Nn + q * 64 + tid] = rprob_s[tid];
  }
}

// ---------------------------------------------------------------------------
extern "C" void kernel_launch(void* const* d_in, const int* in_sizes, int n_in,
                              void* d_out, int out_size, void* d_ws,
                              size_t ws_size, hipStream_t stream) {
  const float* tasks = (const float*)d_in[0];
  const float* constraints = (const float*)d_in[1];
  const int* masks = (const int*)d_in[2];
  const int* topologicals = (const int*)d_in[3];
  const float* w_init1 = (const float*)d_in[4];
  const float* b_init1 = (const float*)d_in[5];
  const float* w_init2 = (const float*)d_in[6];
  const float* b_init2 = (const float*)d_in[7];
  const float* wq = (const float*)d_in[8];
  const float* bq = (const float*)d_in[9];
  const float* wk = (const float*)d_in[10];
  const float* bk = (const float*)d_in[11];
  const float* wv = (const float*)d_in[12];
  const float* bv = (const float*)d_in[13];
  const float* wo = (const float*)d_in[14];
  const float* bo = (const float*)d_in[15];
  const float* w_node1 = (const float*)d_in[16];
  const float* b_node1 = (const float*)d_in[17];
  const float* w_node2 = (const float*)d_in[18];
  const float* b_node2 = (const float*)d_in[19];
  const float* w_ser1 = (const float*)d_in[20];
  const float* b_ser1 = (const float*)d_in[21];
  const float* w_ser2 = (const float*)d_in[22];
  const float* b_ser2 = (const float*)d_in[23];

  float* ws = (float*)d_ws;
  float* node_emb = ws;                             // Q*N*E; reused as gbase
  float* ybuf = node_emb + (size_t)Qn * Nn * En;    // Q*N*E (mha output)
  float* Mt4 = ybuf + (size_t)Qn * Nn * En;         // 128*128 lane-interleaved
  float* dvec = Mt4 + 128 * 128;
  unsigned* keys = (unsigned*)(dvec + 128);         // 128 u32
  float* gbase = node_emb;  // safe: per-block, resid reads precede gbase writes

  setup_kernel<<<130, 128, 0, stream>>>(w_node2, b_node2, w_ser2, b_ser2, Mt4,
                                        dvec, keys);
  init_mlp_kernel<<<Qn, 256, 0, stream>>>(tasks, constraints, w_init1, b_init1,
                                          w_init2, b_init2, node_emb);
  mha_kernel<<<Qn, 256, 0, stream>>>(node_emb, wq, bq, wk, bk, wv, bv, ybuf);
  outgb_kernel<<<Qn, 256, 0, stream>>>(node_emb, ybuf, wo, bo, w_node1,
                                       b_node1, gbase);
  scan_kernel<<<Qn, 256, 0, stream>>>(tasks, masks, topologicals, w_node1,
                                      w_ser1, b_ser1, gbase, Mt4, dvec, keys,
                                      (float*)d_out);
}

// Round 4
// 2081.489 us; speedup vs baseline: 1.1179x; 1.1179x over previous
//
#include <hip/hip_runtime.h>
#include <math.h>

// Problem constants
#define Qn 2048
#define Nn 64
#define Sn 128
#define An 4
#define En 128
#define TASKW 576  // N + 4*S
#define NEGV -1000000000.0f

// ---------------------------------------------------------------------------
// Packed fp32 math (v_pk_fma_f32: 2 x f32 per lane per issue).
// ---------------------------------------------------------------------------
typedef float v2f __attribute__((ext_vector_type(2)));
typedef float v4f __attribute__((ext_vector_type(4)));

__device__ __forceinline__ v2f mkv2(float a, float b) {
  v2f r; r.x = a; r.y = b; return r;
}
__device__ __forceinline__ v2f lo2(v4f v) { v2f r; r.x = v.x; r.y = v.y; return r; }
__device__ __forceinline__ v2f hi2(v4f v) { v2f r; r.x = v.z; r.y = v.w; return r; }
__device__ __forceinline__ void pkfma(v2f& d, v2f a, v2f b) {
  asm("v_pk_fma_f32 %0, %1, %2, %0" : "+v"(d) : "v"(a), "v"(b));
}
// d += broadcast(a.lo) * b   (op_sel routes src0.lo to both result halves)
__device__ __forceinline__ void pkfma_bl(v2f& d, v2f a, v2f b) {
  asm("v_pk_fma_f32 %0, %1, %2, %0 op_sel:[0,0,0] op_sel_hi:[0,1,1]"
      : "+v"(d) : "v"(a), "v"(b));
}
// d += broadcast(a.hi) * b
__device__ __forceinline__ void pkfma_bh(v2f& d, v2f a, v2f b) {
  asm("v_pk_fma_f32 %0, %1, %2, %0 op_sel:[1,0,0] op_sel_hi:[1,1,1]"
      : "+v"(d) : "v"(a), "v"(b));
}

// ---------------------------------------------------------------------------
// Threefry-2x32 (20 rounds), matches JAX's threefry2x32_p exactly.
// ---------------------------------------------------------------------------
__device__ __forceinline__ void threefry2x32(unsigned k0, unsigned k1,
                                             unsigned x0, unsigned x1,
                                             unsigned& o0, unsigned& o1) {
  unsigned ks2 = k0 ^ k1 ^ 0x1BD11BDAu;
  x0 += k0; x1 += k1;
#define TFR(r) { x0 += x1; x1 = (x1 << (r)) | (x1 >> (32 - (r))); x1 ^= x0; }
  TFR(13) TFR(15) TFR(26) TFR(6)
  x0 += k1;  x1 += ks2 + 1u;
  TFR(17) TFR(29) TFR(16) TFR(24)
  x0 += ks2; x1 += k0 + 2u;
  TFR(13) TFR(15) TFR(26) TFR(6)
  x0 += k0;  x1 += k1 + 3u;
  TFR(17) TFR(29) TFR(16) TFR(24)
  x0 += k1;  x1 += ks2 + 4u;
  TFR(13) TFR(15) TFR(26) TFR(6)
  x0 += ks2; x1 += k0 + 5u;
#undef TFR
  o0 = x0; o1 = x1;
}

__device__ __forceinline__ float silu_f(float x) {
  return x / (1.0f + expf(-x));
}
__device__ __forceinline__ float fexp(float x) {
  return __builtin_amdgcn_exp2f(x * 1.44269504088896f);
}
__device__ __forceinline__ float fsilu(float x) {
  const float e = __builtin_amdgcn_exp2f(x * -1.44269504088896f);
  return x * __builtin_amdgcn_rcpf(1.0f + e);
}
__device__ __forceinline__ float flog(float x) {
  return __builtin_amdgcn_logf(x) * 0.69314718055995f;
}

// ---------------------------------------------------------------------------
// Setup: Mt4 = lane-interleaved M (M = w_node2 @ w_ser2^T), dvec, PRNG keys.
// Mt4 layout: element (j,h) stored at Mt4[((j>>2)*128 + h)*4 + (j&3)] so a
// wave of 128 threads (h = tid) reading j-block j4 issues coalesced b128.
// ---------------------------------------------------------------------------
__global__ void setup_kernel(const float* __restrict__ w_node2,
                             const float* __restrict__ b_node2,
                             const float* __restrict__ w_ser2,
                             const float* __restrict__ b_ser2,
                             float* __restrict__ Mt4, float* __restrict__ dvec,
                             unsigned* __restrict__ keys) {
  const int b = blockIdx.x, t = threadIdx.x;
  if (b < 128) {
    float acc = 0.0f;
    for (int e = 0; e < 128; ++e)
      acc = fmaf(w_node2[b * 128 + e], w_ser2[t * 128 + e], acc);
    Mt4[(((b >> 2) * 128) + t) * 4 + (b & 3)] = acc;
  } else if (b == 128) {
    float acc = 0.0f;
    for (int e = 0; e < 128; ++e)
      acc = fmaf(b_node2[e], w_ser2[t * 128 + e], acc);
    dvec[t] = acc;
  } else {
    if (t < 64) {
      unsigned o0, o1;
      threefry2x32(0u, 1u, 0u, (unsigned)t, o0, o1);
      keys[2 * t + 0] = o0;
      keys[2 * t + 1] = o1;
    }
  }
}

// ---------------------------------------------------------------------------
// K1: node_emb = silu(concat(tasks[:,:, :64], cons) @ w1 + b1) @ w2 + b2
// ---------------------------------------------------------------------------
__global__ __launch_bounds__(256, 2)
void init_mlp_kernel(const float* __restrict__ tasks,
                     const float* __restrict__ cons,
                     const float* __restrict__ w1, const float* __restrict__ b1,
                     const float* __restrict__ w2, const float* __restrict__ b2,
                     float* __restrict__ node_emb) {
  const int q = blockIdx.x, tid = threadIdx.x;
  const int lane = tid & 127, half = tid >> 7;
  __shared__ __align__(16) float xr[2][68];
  __shared__ __align__(16) float sgb[2][128];
  v2f w1p[34], w2p[64];
#pragma unroll
  for (int i = 0; i < 34; ++i)
    w1p[i] = mkv2(w1[(2 * i) * 128 + lane], w1[(2 * i + 1) * 128 + lane]);
#pragma unroll
  for (int j = 0; j < 64; ++j)
    w2p[j] = mkv2(w2[(2 * j) * 128 + lane], w2[(2 * j + 1) * 128 + lane]);
  const float bb1 = b1[lane], bb2 = b2[lane];
  for (int r = 0; r < 64; r += 2) {
    if (tid < 136) {
      const int rr = tid / 68, j = tid - rr * 68;
      xr[rr][j] = (j < 64) ? tasks[(q * 64 + r + rr) * TASKW + j]
                           : cons[q * 4 + (j - 64)];
    }
    __syncthreads();
    v2f gp = mkv2(0.0f, 0.0f);
    const v4f* xr4 = (const v4f*)&xr[half][0];
#pragma unroll
    for (int i = 0; i < 17; ++i) {
      const v4f x = xr4[i];
      pkfma(gp, lo2(x), w1p[2 * i]);
      pkfma(gp, hi2(x), w1p[2 * i + 1]);
    }
    const float g = gp.x + gp.y + bb1;
    sgb[half][lane] = silu_f(g);
    __syncthreads();
    v2f op = mkv2(0.0f, 0.0f);
    const v4f* sgb4 = (const v4f*)&sgb[half][0];
#pragma unroll
    for (int j = 0; j < 32; ++j) {
      const v4f s = sgb4[j];
      pkfma(op, lo2(s), w2p[2 * j]);
      pkfma(op, hi2(s), w2p[2 * j + 1]);
    }
    node_emb[(q * 64 + r + half) * 128 + lane] = op.x + op.y + bb2;
    __syncthreads();
  }
}

// ---------------------------------------------------------------------------
// K2: fused MHA (QKV + scores + softmax + AV), b128 LDS reads throughout.
// ---------------------------------------------------------------------------
__global__ __launch_bounds__(256, 2)
void mha_kernel(const float* __restrict__ node_emb,
                const float* __restrict__ wq, const float* __restrict__ bq,
                const float* __restrict__ wk, const float* __restrict__ bk,
                const float* __restrict__ wv, const float* __restrict__ bv,
                float* __restrict__ y_out) {
  const int q = blockIdx.x, tid = threadIdx.x;
  __shared__ __align__(16) float xs[64][132];
  __shared__ __align__(16) float qh[64][20];
  __shared__ __align__(16) float kh[64][20];
  __shared__ __align__(16) float vt[16][68];
  __shared__ __align__(16) float pool[3 * 16 * 132];  // wht[3][16][132] U at[64][68]
  float (*wht)[16][132] = (float (*)[16][132])pool;
  float (*at)[68] = (float (*)[68])pool;

  for (int idx = tid; idx < 64 * 32; idx += 256) {
    const int n = idx >> 5, e4 = idx & 31;
    *(v4f*)&xs[n][4 * e4] =
        *(const v4f*)&node_emb[(q * 64 + n) * 128 + 4 * e4];
  }
  __syncthreads();

  const int d16 = tid >> 4;  // 0..15
  const int ng = tid & 15;   // 0..15

  for (int hd = 0; hd < 8; ++hd) {
    for (int idx = tid; idx < 3 * 128 * 16; idx += 256) {
      const int m = idx >> 11, k = (idx >> 4) & 127, d = idx & 15;
      const float* W = (m == 0) ? wq : (m == 1) ? wk : wv;
      wht[m][d][k] = W[k * 128 + hd * 16 + d];
    }
    __syncthreads();

    {
      const float bqv = bq[hd * 16 + d16];
      const float bkv = bk[hd * 16 + d16];
      const float bvv = bv[hd * 16 + d16];
      const v4f* wq4 = (const v4f*)&wht[0][d16][0];
      const v4f* wk4 = (const v4f*)&wht[1][d16][0];
      const v4f* wv4 = (const v4f*)&wht[2][d16][0];
      const v4f* xr0 = (const v4f*)&xs[ng][0];
      const v4f* xr1 = (const v4f*)&xs[ng + 16][0];
      const v4f* xr2 = (const v4f*)&xs[ng + 32][0];
      const v4f* xr3 = (const v4f*)&xs[ng + 48][0];
      v2f aq0 = mkv2(0, 0), aq1 = mkv2(0, 0), aq2 = mkv2(0, 0), aq3 = mkv2(0, 0);
      v2f ak0 = mkv2(0, 0), ak1 = mkv2(0, 0), ak2 = mkv2(0, 0), ak3 = mkv2(0, 0);
      v2f av0 = mkv2(0, 0), av1 = mkv2(0, 0), av2 = mkv2(0, 0), av3 = mkv2(0, 0);
#pragma unroll 4
      for (int kk = 0; kk < 32; ++kk) {
        const v4f wqv = wq4[kk], wkv = wk4[kk], wvv = wv4[kk];
        const v4f x0 = xr0[kk], x1 = xr1[kk], x2 = xr2[kk], x3 = xr3[kk];
        const v2f wqa = lo2(wqv), wqb = hi2(wqv);
        const v2f wka = lo2(wkv), wkb = hi2(wkv);
        const v2f wva = lo2(wvv), wvb = hi2(wvv);
        const v2f x0a = lo2(x0), x0b = hi2(x0);
        const v2f x1a = lo2(x1), x1b = hi2(x1);
        const v2f x2a = lo2(x2), x2b = hi2(x2);
        const v2f x3a = lo2(x3), x3b = hi2(x3);
        pkfma(aq0, x0a, wqa); pkfma(aq0, x0b, wqb);
        pkfma(aq1, x1a, wqa); pkfma(aq1, x1b, wqb);
        pkfma(aq2, x2a, wqa); pkfma(aq2, x2b, wqb);
        pkfma(aq3, x3a, wqa); pkfma(aq3, x3b, wqb);
        pkfma(ak0, x0a, wka); pkfma(ak0, x0b, wkb);
        pkfma(ak1, x1a, wka); pkfma(ak1, x1b, wkb);
        pkfma(ak2, x2a, wka); pkfma(ak2, x2b, wkb);
        pkfma(ak3, x3a, wka); pkfma(ak3, x3b, wkb);
        pkfma(av0, x0a, wva); pkfma(av0, x0b, wvb);
        pkfma(av1, x1a, wva); pkfma(av1, x1b, wvb);
        pkfma(av2, x2a, wva); pkfma(av2, x2b, wvb);
        pkfma(av3, x3a, wva); pkfma(av3, x3b, wvb);
      }
      qh[ng][d16] = fmaxf(aq0.x + aq0.y + bqv, 0.0f);
      qh[ng + 16][d16] = fmaxf(aq1.x + aq1.y + bqv, 0.0f);
      qh[ng + 32][d16] = fmaxf(aq2.x + aq2.y + bqv, 0.0f);
      qh[ng + 48][d16] = fmaxf(aq3.x + aq3.y + bqv, 0.0f);
      kh[ng][d16] = fmaxf(ak0.x + ak0.y + bkv, 0.0f);
      kh[ng + 16][d16] = fmaxf(ak1.x + ak1.y + bkv, 0.0f);
      kh[ng + 32][d16] = fmaxf(ak2.x + ak2.y + bkv, 0.0f);
      kh[ng + 48][d16] = fmaxf(ak3.x + ak3.y + bkv, 0.0f);
      vt[d16][ng] = fmaxf(av0.x + av0.y + bvv, 0.0f);
      vt[d16][ng + 16] = fmaxf(av1.x + av1.y + bvv, 0.0f);
      vt[d16][ng + 32] = fmaxf(av2.x + av2.y + bvv, 0.0f);
      vt[d16][ng + 48] = fmaxf(av3.x + av3.y + bvv, 0.0f);
    }
    __syncthreads();

    {
      const int n = tid >> 2, mg = tid & 3;
      v4f qv[4];
      const v4f* qrow = (const v4f*)&qh[n][0];
#pragma unroll
      for (int kk = 0; kk < 4; ++kk) qv[kk] = qrow[kk];
#pragma unroll 4
      for (int jj = 0; jj < 16; ++jj) {
        const int m = mg + 4 * jj;
        const v4f* krow = (const v4f*)&kh[m][0];
        v2f accp = mkv2(0.0f, 0.0f);
#pragma unroll
        for (int kk = 0; kk < 4; ++kk) {
          const v4f kv = krow[kk];
          pkfma(accp, lo2(qv[kk]), lo2(kv));
          pkfma(accp, hi2(qv[kk]), hi2(kv));
        }
        at[n][m] = (accp.x + accp.y) * 0.25f;
      }
    }
    __syncthreads();

    {
      const int r = tid >> 2, p = tid & 3;
      const v4f* arow = (const v4f*)&at[r][p * 16];
      v4f av[4];
#pragma unroll
      for (int u = 0; u < 4; ++u) av[u] = arow[u];
      float mx = -1e30f;
#pragma unroll
      for (int u = 0; u < 4; ++u) {
        mx = fmaxf(mx, fmaxf(fmaxf(av[u].x, av[u].y), fmaxf(av[u].z, av[u].w)));
      }
      mx = fmaxf(mx, __shfl_xor(mx, 1, 64));
      mx = fmaxf(mx, __shfl_xor(mx, 2, 64));
      float s = 0.0f;
#pragma unroll
      for (int u = 0; u < 4; ++u) {
        av[u].x = fexp(av[u].x - mx); av[u].y = fexp(av[u].y - mx);
        av[u].z = fexp(av[u].z - mx); av[u].w = fexp(av[u].w - mx);
        s += av[u].x + av[u].y + av[u].z + av[u].w;
      }
      s += __shfl_xor(s, 1, 64);
      s += __shfl_xor(s, 2, 64);
      const float rs = __builtin_amdgcn_rcpf(s);
      v4f* wrow = (v4f*)&at[r][p * 16];
#pragma unroll
      for (int u = 0; u < 4; ++u) {
        av[u].x *= rs; av[u].y *= rs; av[u].z *= rs; av[u].w *= rs;
        wrow[u] = av[u];
      }
    }
    __syncthreads();

    {
      const int dd = tid & 15, ngr = tid >> 4;
      const v4f* vrow = (const v4f*)&vt[dd][0];
      const v4f* ar0 = (const v4f*)&at[ngr][0];
      const v4f* ar1 = (const v4f*)&at[ngr + 16][0];
      const v4f* ar2 = (const v4f*)&at[ngr + 32][0];
      const v4f* ar3 = (const v4f*)&at[ngr + 48][0];
      v2f ac0 = mkv2(0, 0), ac1 = mkv2(0, 0), ac2 = mkv2(0, 0), ac3 = mkv2(0, 0);
#pragma unroll 4
      for (int kk = 0; kk < 16; ++kk) {
        const v4f vv = vrow[kk];
        const v2f va = lo2(vv), vb = hi2(vv);
        const v4f a0 = ar0[kk], a1 = ar1[kk], a2 = ar2[kk], a3 = ar3[kk];
        pkfma(ac0, lo2(a0), va); pkfma(ac0, hi2(a0), vb);
        pkfma(ac1, lo2(a1), va); pkfma(ac1, hi2(a1), vb);
        pkfma(ac2, lo2(a2), va); pkfma(ac2, hi2(a2), vb);
        pkfma(ac3, lo2(a3), va); pkfma(ac3, hi2(a3), vb);
      }
      y_out[(q * 64 + ngr) * 128 + hd * 16 + dd] = ac0.x + ac0.y;
      y_out[(q * 64 + ngr + 16) * 128 + hd * 16 + dd] = ac1.x + ac1.y;
      y_out[(q * 64 + ngr + 32) * 128 + hd * 16 + dd] = ac2.x + ac2.y;
      y_out[(q * 64 + ngr + 48) * 128 + hd * 16 + dd] = ac3.x + ac3.y;
    }
    __syncthreads();
  }
}

// ---------------------------------------------------------------------------
// K3 (fused): nodes = relu(y @ wo + bo) + resid; gbase = nodes @ w_node1 + b
// ---------------------------------------------------------------------------
__global__ __launch_bounds__(256, 2)
void outgb_kernel(const float* __restrict__ resid, const float* __restrict__ y,
                  const float* __restrict__ wo, const float* __restrict__ bo,
                  const float* __restrict__ w_node1,
                  const float* __restrict__ b_node1,
                  float* __restrict__ gbase) {
  const int q = blockIdx.x, tid = threadIdx.x;
  __shared__ __align__(16) float ys[64][132];
  __shared__ __align__(16) float wot[32][132];
  for (int idx = tid; idx < 64 * 32; idx += 256) {
    const int n = idx >> 5, e4 = idx & 31;
    *(v4f*)&ys[n][4 * e4] = *(const v4f*)&y[(q * 64 + n) * 128 + 4 * e4];
  }
  const int cg = tid & 15, ngr = tid >> 4;
  float nodes[4][8];  // [n-group][tile*2 + {0,1}]

#pragma unroll
  for (int tile = 0; tile < 4; ++tile) {
    const int c0 = 32 * tile;
    __syncthreads();
    for (int idx = tid; idx < 32 * 128; idx += 256) {
      const int k = idx >> 5, c = idx & 31;
      wot[c][k] = wo[k * 128 + c0 + c];
    }
    __syncthreads();
    const int c = c0 + 2 * cg;
    const v4f* w0 = (const v4f*)&wot[2 * cg][0];
    const v4f* w1 = (const v4f*)&wot[2 * cg + 1][0];
    const v4f* yr0 = (const v4f*)&ys[ngr][0];
    const v4f* yr1 = (const v4f*)&ys[ngr + 16][0];
    const v4f* yr2 = (const v4f*)&ys[ngr + 32][0];
    const v4f* yr3 = (const v4f*)&ys[ngr + 48][0];
    v2f a00 = mkv2(0, 0), a01 = mkv2(0, 0), a10 = mkv2(0, 0), a11 = mkv2(0, 0);
    v2f a20 = mkv2(0, 0), a21 = mkv2(0, 0), a30 = mkv2(0, 0), a31 = mkv2(0, 0);
#pragma unroll 4
    for (int kk = 0; kk < 32; ++kk) {
      const v4f wv0 = w0[kk], wv1 = w1[kk];
      const v2f w0a = lo2(wv0), w0b = hi2(wv0);
      const v2f w1a = lo2(wv1), w1b = hi2(wv1);
      const v4f x0 = yr0[kk], x1 = yr1[kk], x2 = yr2[kk], x3 = yr3[kk];
      pkfma(a00, lo2(x0), w0a); pkfma(a00, hi2(x0), w0b);
      pkfma(a01, lo2(x0), w1a); pkfma(a01, hi2(x0), w1b);
      pkfma(a10, lo2(x1), w0a); pkfma(a10, hi2(x1), w0b);
      pkfma(a11, lo2(x1), w1a); pkfma(a11, hi2(x1), w1b);
      pkfma(a20, lo2(x2), w0a); pkfma(a20, hi2(x2), w0b);
      pkfma(a21, lo2(x2), w1a); pkfma(a21, hi2(x2), w1b);
      pkfma(a30, lo2(x3), w0a); pkfma(a30, hi2(x3), w0b);
      pkfma(a31, lo2(x3), w1a); pkfma(a31, hi2(x3), w1b);
    }
    const float b0v = bo[c], b1v = bo[c + 1];
#define PROJ_EMIT(J, A0, A1)                                                  \
    {                                                                         \
      const int n = ngr + 16 * J;                                             \
      const float2 res = *(const float2*)&resid[(q * 64 + n) * 128 + c];      \
      nodes[J][2 * tile] = fmaxf(A0.x + A0.y + b0v, 0.0f) + res.x;            \
      nodes[J][2 * tile + 1] = fmaxf(A1.x + A1.y + b1v, 0.0f) + res.y;        \
    }
    PROJ_EMIT(0, a00, a01)
    PROJ_EMIT(1, a10, a11)
    PROJ_EMIT(2, a20, a21)
    PROJ_EMIT(3, a30, a31)
#undef PROJ_EMIT
  }
  __syncthreads();
#pragma unroll
  for (int j = 0; j < 4; ++j) {
    const int n = ngr + 16 * j;
#pragma unroll
    for (int tile = 0; tile < 4; ++tile) {
      *(float2*)&ys[n][32 * tile + 2 * cg] =
          make_float2(nodes[j][2 * tile], nodes[j][2 * tile + 1]);
    }
  }

#pragma unroll
  for (int tile = 0; tile < 4; ++tile) {
    const int c0 = 32 * tile;
    __syncthreads();
    for (int idx = tid; idx < 32 * 128; idx += 256) {
      const int k = idx >> 5, c = idx & 31;
      wot[c][k] = w_node1[k * 128 + c0 + c];
    }
    __syncthreads();
    const int c = c0 + 2 * cg;
    const v4f* w0 = (const v4f*)&wot[2 * cg][0];
    const v4f* w1 = (const v4f*)&wot[2 * cg + 1][0];
    const v4f* yr0 = (const v4f*)&ys[ngr][0];
    const v4f* yr1 = (const v4f*)&ys[ngr + 16][0];
    const v4f* yr2 = (const v4f*)&ys[ngr + 32][0];
    const v4f* yr3 = (const v4f*)&ys[ngr + 48][0];
    v2f a00 = mkv2(0, 0), a01 = mkv2(0, 0), a10 = mkv2(0, 0), a11 = mkv2(0, 0);
    v2f a20 = mkv2(0, 0), a21 = mkv2(0, 0), a30 = mkv2(0, 0), a31 = mkv2(0, 0);
#pragma unroll 4
    for (int kk = 0; kk < 32; ++kk) {
      const v4f wv0 = w0[kk], wv1 = w1[kk];
      const v2f w0a = lo2(wv0), w0b = hi2(wv0);
      const v2f w1a = lo2(wv1), w1b = hi2(wv1);
      const v4f x0 = yr0[kk], x1 = yr1[kk], x2 = yr2[kk], x3 = yr3[kk];
      pkfma(a00, lo2(x0), w0a); pkfma(a00, hi2(x0), w0b);
      pkfma(a01, lo2(x0), w1a); pkfma(a01, hi2(x0), w1b);
      pkfma(a10, lo2(x1), w0a); pkfma(a10, hi2(x1), w0b);
      pkfma(a11, lo2(x1), w1a); pkfma(a11, hi2(x1), w1b);
      pkfma(a20, lo2(x2), w0a); pkfma(a20, hi2(x2), w0b);
      pkfma(a21, lo2(x2), w1a); pkfma(a21, hi2(x2), w1b);
      pkfma(a30, lo2(x3), w0a); pkfma(a30, hi2(x3), w0b);
      pkfma(a31, lo2(x3), w1a); pkfma(a31, hi2(x3), w1b);
    }
    const float b0v = b_node1[c], b1v = b_node1[c + 1];
#define GB_EMIT(J, A0, A1)                                                    \
    {                                                                         \
      const int n = ngr + 16 * J;                                             \
      float2 o;                                                               \
      o.x = A0.x + A0.y + b0v;                                                \
      o.y = A1.x + A1.y + b1v;                                                \
      *(float2*)&gbase[(q * 64 + n) * 128 + c] = o;                           \
    }
    GB_EMIT(0, a00, a01)
    GB_EMIT(1, a10, a11)
    GB_EMIT(2, a20, a21)
    GB_EMIT(3, a30, a31)
#undef GB_EMIT
  }
}

// ---------------------------------------------------------------------------
// K4: 64-step scan, one workgroup per q. v4: register diet for the 64-VGPR
// occupancy bucket (8 blocks/CU) with ZERO spill:
//  - prefetch loads go straight to LDS in P1 (no registers held across phases;
//    vmcnt stall hidden by cross-block TLP);
//  - qw/dvec live in LDS (1 read/step) instead of registers;
//  - matvec reads lane-interleaved Mt4 from L2 (no 64-VGPR M array);
//  - 4 barriers/step; logits on all 256 threads.
// ---------------------------------------------------------------------------
__global__ __launch_bounds__(256, 8)
void scan_kernel(const float* __restrict__ tasks, const int* __restrict__ masks,
                 const int* __restrict__ topologicals,
                 const float* __restrict__ w_node1,
                 const float* __restrict__ w_ser1,
                 const float* __restrict__ b_ser1,
                 const float* __restrict__ gbase,
                 const float* __restrict__ Mt4, const float* __restrict__ dvec,
                 const unsigned* __restrict__ keys, float* __restrict__ out) {
  const int q = blockIdx.x, tid = threadIdx.x;
  const int wl = tid & 63, wave = tid >> 6;
  const int g16 = tid >> 4, oo = tid & 15;

  __shared__ __align__(16) float task_s[2][TASKW];
  __shared__ __align__(16) float gb_s[2][128];
  __shared__ int mask_s[2][128];
  __shared__ int topo_s[64];
  __shared__ __align__(16) float sg[128];
  __shared__ __align__(16) v4f wa_s[64];   // w_ser1 pairs, cols 0,1
  __shared__ __align__(16) v4f wb_s[64];   // w_ser1 pairs, cols 2,3
  __shared__ __align__(16) v2f bp_s[64];   // b_ser1 pairs
  __shared__ __align__(16) v2f up_s[64];   // uu pairs (per step)
  __shared__ __align__(16) v4f qw4_s[128]; // w_node1 rows 128..131 packed
  __shared__ __align__(16) float dvs[128];
  __shared__ float gn_s[128];              // gumbel noise, compact order
  __shared__ float lcomp_s[128];           // logits, compact order
  __shared__ int act_s[128];               // active service indices
  __shared__ float qr_s[64];               // qos col 0 (only live column)
  __shared__ float ridx_s[64], rprob_s[64];
  __shared__ unsigned keys_s[128];
  __shared__ int na_s;

  if (tid < 64) {
    topo_s[tid] = topologicals[q * 64 + tid];
    const int j = tid;
    v4f wa, wb;
    wa.x = w_ser1[0 * 128 + 2 * j]; wa.y = w_ser1[0 * 128 + 2 * j + 1];
    wa.z = w_ser1[1 * 128 + 2 * j]; wa.w = w_ser1[1 * 128 + 2 * j + 1];
    wb.x = w_ser1[2 * 128 + 2 * j]; wb.y = w_ser1[2 * 128 + 2 * j + 1];
    wb.z = w_ser1[3 * 128 + 2 * j]; wb.w = w_ser1[3 * 128 + 2 * j + 1];
    wa_s[j] = wa;
    wb_s[j] = wb;
    bp_s[j] = mkv2(b_ser1[2 * j], b_ser1[2 * j + 1]);
    qr_s[tid] = 3.0f;
    ridx_s[tid] = 0.0f;
    rprob_s[tid] = 0.0f;
  }
  if (tid < 128) {
    keys_s[tid] = keys[tid];
    dvs[tid] = dvec[tid];
    v4f qp;
    qp.x = w_node1[128 * 128 + tid];
    qp.y = w_node1[129 * 128 + tid];
    qp.z = w_node1[130 * 128 + tid];
    qp.w = w_node1[131 * 128 + tid];
    qw4_s[tid] = qp;
  }
  float ava = 1.0f, tp = 3.0f, rel = 1.0f;  // per-thread redundant state
  __syncthreads();

  // Prologue: stage step 0 into buffer 0
  {
    const int topo0 = topo_s[63];
    if (tid < 144)
      ((float4*)task_s[0])[tid] =
          ((const float4*)(tasks + (size_t)(q * 64 + topo0) * TASKW))[tid];
    if (tid < 128) {
      gb_s[0][tid] = gbase[(q * 64 + topo0) * 128 + tid];
      mask_s[0][tid] = masks[(q * 64 + topo0) * 128 + tid];
    }
  }
  __syncthreads();

  for (int t = 0; t < 64; ++t) {
    const int cur = t & 1, nxt = cur ^ 1;
    const int topo = topo_s[63 - t];
    const int tn = (t < 63) ? t + 1 : 63;
    const int ntopo = topo_s[63 - tn];

    // --- Phase 1: waves 0/1 rt + sg; wave 2 prefetch gb/mask -> LDS[nxt]
    // + ballot-compact; wave 3 prefetch task rows -> LDS[nxt].
    float rt = 0.0f;
    if (wave < 2) {
      float p = task_s[cur][wl] * qr_s[wl];
#pragma unroll
      for (int o = 32; o > 0; o >>= 1) p = fmaxf(p, __shfl_xor(p, o, 64));
      rt = p;
      const v4f qp = qw4_s[tid];
      float g = gb_s[cur][tid];
      g = fmaf(rt, qp.x, g);
      g = fmaf(ava, qp.y, g);
      g = fmaf(tp, qp.z, g);
      g = fmaf(rel, qp.w, g);
      sg[tid] = fsilu(g);
    } else if (wave == 2) {
      const float g0 = gbase[(q * 64 + ntopo) * 128 + wl];
      const float g1 = gbase[(q * 64 + ntopo) * 128 + wl + 64];
      const int m0n = masks[(q * 64 + ntopo) * 128 + wl];
      const int m1n = masks[(q * 64 + ntopo) * 128 + wl + 64];
      // compact current mask while loads are in flight
      const int m0 = mask_s[cur][wl] != 0;
      const int m1 = mask_s[cur][wl + 64] != 0;
      const unsigned long long b0 = __ballot(m0);
      const unsigned long long b1 = __ballot(m1);
      const unsigned long long lt = (1ull << wl) - 1ull;
      const int c0 = __popcll(b0);
      if (m0) act_s[__popcll(b0 & lt)] = wl;
      if (m1) act_s[c0 + __popcll(b1 & lt)] = wl + 64;
      if (wl == 0) na_s = c0 + __popcll(b1);
      gb_s[nxt][wl] = g0;
      gb_s[nxt][wl + 64] = g1;
      mask_s[nxt][wl] = m0n;
      mask_s[nxt][wl + 64] = m1n;
    } else {
      const float4* src = (const float4*)(tasks + (size_t)(q * 64 + ntopo) * TASKW);
      float4* dst = (float4*)task_s[nxt];
      dst[wl] = src[wl];
      dst[wl + 64] = src[wl + 64];
      if (wl < 16) dst[wl + 128] = src[wl + 128];
    }
    __syncthreads();  // B_a : sg, act, na visible
    const int na = na_s;

    // --- Phase 2: waves 0/1 matvec u = sg @ M + dvec from L2-resident Mt4;
    // waves 2/3 gumbel-noise precompute for active slots.
    if (tid < 128) {
      v2f a0 = mkv2(0.0f, 0.0f), a1 = mkv2(0.0f, 0.0f);
      const v4f* Mg = ((const v4f*)Mt4) + tid;
      const v4f* sg4 = (const v4f*)sg;
#pragma unroll 8
      for (int j4 = 0; j4 < 32; ++j4) {
        const v4f m = Mg[j4 * 128];
        const v4f s = sg4[j4];
        pkfma(a0, lo2(s), lo2(m));
        pkfma(a1, hi2(s), hi2(m));
      }
      const float u = a0.x + a0.y + a1.x + a1.y + dvs[tid];
      const float u2 = __shfl_xor(u, 1, 64);
      if ((tid & 1) == 0) up_s[tid >> 1] = mkv2(u, u2);
    } else {
      const int slot = tid - 128;
      if (slot < na) {
        const int s = act_s[slot];
        unsigned o0, o1;
        threefry2x32(keys_s[2 * t], keys_s[2 * t + 1], 0u,
                     (unsigned)(q * 128 + s), o0, o1);
        const unsigned bits = o0 ^ o1;
        const float f = __uint_as_float((bits >> 9) | 0x3f800000u) - 1.0f;
        const float uu = (f > 0.0f) ? f : 1.17549435e-38f;
        gn_s[slot] = -flog(-flog(uu));
      }
    }
    __syncthreads();  // B_b : up, gn visible

    // --- Phase 3: logits on all 256 threads (16 thr per 4 services).
    auto logits_block = [&](const int sl0) {
      const int s0 = (sl0 + 0 < na) ? act_s[sl0 + 0] : 0;
      const int s1 = (sl0 + 1 < na) ? act_s[sl0 + 1] : 0;
      const int s2 = (sl0 + 2 < na) ? act_s[sl0 + 2] : 0;
      const int s3 = (sl0 + 3 < na) ? act_s[sl0 + 3] : 0;
      const v4f svA = *(const v4f*)&task_s[cur][64 + 4 * s0];
      const v4f svB = *(const v4f*)&task_s[cur][64 + 4 * s1];
      const v4f svC = *(const v4f*)&task_s[cur][64 + 4 * s2];
      const v4f svD = *(const v4f*)&task_s[cur][64 + 4 * s3];
      v2f ac0 = mkv2(0.0f, 0.0f), ac1 = mkv2(0.0f, 0.0f);
      v2f ac2 = mkv2(0.0f, 0.0f), ac3 = mkv2(0.0f, 0.0f);
#pragma unroll
      for (int jj = 0; jj < 4; ++jj) {
        const int j = oo + 16 * jj;
        const v4f wA = wa_s[j];
        const v4f wB = wb_s[j];
        const v2f bp = bp_s[j];
        const v2f up = up_s[j];
#define SRV(AC, SV)                                                           \
        {                                                                     \
          v2f p = bp;                                                         \
          pkfma_bl(p, lo2(SV), lo2(wA));                                      \
          pkfma_bh(p, lo2(SV), hi2(wA));                                      \
          pkfma_bl(p, hi2(SV), lo2(wB));                                      \
          pkfma_bh(p, hi2(SV), hi2(wB));                                      \
          const float ex = __builtin_amdgcn_exp2f(p.x * -1.44269504088896f);  \
          const float ey = __builtin_amdgcn_exp2f(p.y * -1.44269504088896f);  \
          const float rx = __builtin_amdgcn_rcpf(1.0f + ex);                  \
          const float ry = __builtin_amdgcn_rcpf(1.0f + ey);                  \
          pkfma(AC, mkv2(p.x * rx, p.y * ry), up);                            \
        }
        SRV(ac0, svA)
        SRV(ac1, svB)
        SRV(ac2, svC)
        SRV(ac3, svD)
#undef SRV
      }
      float l0 = ac0.x + ac0.y, l1 = ac1.x + ac1.y;
      float l2 = ac2.x + ac2.y, l3 = ac3.x + ac3.y;
      l0 += __shfl_xor(l0, 1, 64); l0 += __shfl_xor(l0, 2, 64);
      l0 += __shfl_xor(l0, 4, 64); l0 += __shfl_xor(l0, 8, 64);
      l1 += __shfl_xor(l1, 1, 64); l1 += __shfl_xor(l1, 2, 64);
      l1 += __shfl_xor(l1, 4, 64); l1 += __shfl_xor(l1, 8, 64);
      l2 += __shfl_xor(l2, 1, 64); l2 += __shfl_xor(l2, 2, 64);
      l2 += __shfl_xor(l2, 4, 64); l2 += __shfl_xor(l2, 8, 64);
      l3 += __shfl_xor(l3, 1, 64); l3 += __shfl_xor(l3, 2, 64);
      l3 += __shfl_xor(l3, 4, 64); l3 += __shfl_xor(l3, 8, 64);
      if (oo == 0) {
        if (sl0 + 3 < na) {
          *(float4*)&lcomp_s[sl0] = make_float4(l0, l1, l2, l3);
        } else {
          if (sl0 + 0 < na) lcomp_s[sl0 + 0] = l0;
          if (sl0 + 1 < na) lcomp_s[sl0 + 1] = l1;
          if (sl0 + 2 < na) lcomp_s[sl0 + 2] = l2;
        }
      }
    };
    if (16 * wave < na) logits_block(4 * g16);
    if (64 + 16 * wave < na) logits_block(64 + 4 * g16);
    __syncthreads();  // B_c : lcomp visible

    // --- Phase 4: per-wave redundant argmax; wave 3 softmax normalizer;
    // state update on all threads.
    float la = -3.0e38f, lb = -3.0e38f;
    if (wl < na) la = lcomp_s[wl] + gn_s[wl];
    if (wl + 64 < na) lb = lcomp_s[wl + 64] + gn_s[wl + 64];
    float z = la;
    int zi = wl;
    if (lb > z) { z = lb; zi = wl + 64; }
#pragma unroll
    for (int o = 32; o > 0; o >>= 1) {
      const float zo = __shfl_xor(z, o, 64);
      const int io = __shfl_xor(zi, o, 64);
      if (zo > z || (zo == z && io < zi)) { z = zo; zi = io; }
    }
    const int si = act_s[zi];
    if (wave == 3) {
      const float ma = (wl < na) ? lcomp_s[wl] : -3.0e38f;
      const float mb = (wl + 64 < na) ? lcomp_s[wl + 64] : -3.0e38f;
      float mx = fmaxf(ma, mb);
#pragma unroll
      for (int o = 32; o > 0; o >>= 1) mx = fmaxf(mx, __shfl_xor(mx, o, 64));
      float e = fexp(ma - mx) + fexp(mb - mx);
#pragma unroll
      for (int o = 32; o > 0; o >>= 1) e += __shfl_xor(e, o, 64);
      if (wl == 0)
        rprob_s[topo] += fexp(lcomp_s[zi] - mx) * __builtin_amdgcn_rcpf(e);
    }
    {
      const float s1v = task_s[cur][64 + 4 * si + 1];
      const float s2v = task_s[cur][64 + 4 * si + 2];
      const float s3v = task_s[cur][64 + 4 * si + 3];
      if (tid == 0) {
        const float s0v = task_s[cur][64 + 4 * si];
        qr_s[topo] = s0v + rt;
        ridx_s[topo] += (float)si;
      }
      ava = s1v * ava;
      tp = fminf(s2v, tp);
      rel = s3v * rel;
    }
    __syncthreads();  // B_final
  }
  if (tid < 64) {
    out[q * 64 + tid] = ridx_s[tid];
    out[Qn * Nn + q * 64 + tid] = rprob_s[tid];
  }
}

// ---------------------------------------------------------------------------
extern "C" void kernel_launch(void* const* d_in, const int* in_sizes, int n_in,
                              void* d_out, int out_size, void* d_ws,
                              size_t ws_size, hipStream_t stream) {
  const float* tasks = (const float*)d_in[0];
  const float* constraints = (const float*)d_in[1];
  const int* masks = (const int*)d_in[2];
  const int* topologicals = (const int*)d_in[3];
  const float* w_init1 = (const float*)d_in[4];
  const float* b_init1 = (const float*)d_in[5];
  const float* w_init2 = (const float*)d_in[6];
  const float* b_init2 = (const float*)d_in[7];
  const float* wq = (const float*)d_in[8];
  const float* bq = (const float*)d_in[9];
  const float* wk = (const float*)d_in[10];
  const float* bk = (const float*)d_in[11];
  const float* wv = (const float*)d_in[12];
  const float* bv = (const float*)d_in[13];
  const float* wo = (const float*)d_in[14];
  const float* bo = (const float*)d_in[15];
  const float* w_node1 = (const float*)d_in[16];
  const float* b_node1 = (const float*)d_in[17];
  const float* w_node2 = (const float*)d_in[18];
  const float* b_node2 = (const float*)d_in[19];
  const float* w_ser1 = (const float*)d_in[20];
  const float* b_ser1 = (const float*)d_in[21];
  const float* w_ser2 = (const float*)d_in[22];
  const float* b_ser2 = (const float*)d_in[23];

  float* ws = (float*)d_ws;
  float* node_emb = ws;                             // Q*N*E; reused as gbase
  float* ybuf = node_emb + (size_t)Qn * Nn * En;    // Q*N*E (mha output)
  float* Mt4 = ybuf + (size_t)Qn * Nn * En;         // 128*128 lane-interleaved
  float* dvec = Mt4 + 128 * 128;
  unsigned* keys = (unsigned*)(dvec + 128);         // 128 u32
  float* gbase = node_emb;  // safe: per-block, resid reads precede gbase writes

  setup_kernel<<<130, 128, 0, stream>>>(w_node2, b_node2, w_ser2, b_ser2, Mt4,
                                        dvec, keys);
  init_mlp_kernel<<<Qn, 256, 0, stream>>>(tasks, constraints, w_init1, b_init1,
                                          w_init2, b_init2, node_emb);
  mha_kernel<<<Qn, 256, 0, stream>>>(node_emb, wq, bq, wk, bk, wv, bv, ybuf);
  outgb_kernel<<<Qn, 256, 0, stream>>>(node_emb, ybuf, wo, bo, w_node1,
                                       b_node1, gbase);
  scan_kernel<<<Qn, 256, 0, stream>>>(tasks, masks, topologicals, w_node1,
                                      w_ser1, b_ser1, gbase, Mt4, dvec, keys,
                                      (float*)d_out);
}